// Round 13
// baseline (214.427 us; speedup 1.0000x reference)
//
#include <hip/hip_runtime.h>
#include <math.h>

#define L_SEQ 1024
#define TOPK 6
#define SSTR 1057   // plane stride (floats): 32*33+1 (bank-skewed)
#define IMOFF 4228  // im planes offset = 4*SSTR
#define NFBLK 2048  // one (b,h,e-octet) per block

// W32^m = e^{-2*pi*i*m/32}, compile-time constants
__device__ constexpr float TW32R[16] = {
  1.f, 0.98078528f, 0.92387953f, 0.83146961f, 0.70710678f, 0.55557023f,
  0.38268343f, 0.19509032f, 0.f, -0.19509032f, -0.38268343f, -0.55557023f,
  -0.70710678f, -0.83146961f, -0.92387953f, -0.98078528f};
__device__ constexpr float TW32I[16] = {
  0.f, -0.19509032f, -0.38268343f, -0.55557023f, -0.70710678f, -0.83146961f,
  -0.92387953f, -0.98078528f, -1.f, -0.98078528f, -0.92387953f, -0.83146961f,
  -0.70710678f, -0.55557023f, -0.38268343f, -0.19509032f};

// radix-2 DIT stage; m_==0 / m_==8 (W=1 / W=-i) fold at compile time.
#define FFTSTAGE(M, H, SH)                                                \
  _Pragma("unroll")                                                       \
  for (int k_ = 0; k_ < 32; k_ += (M)) {                                  \
    _Pragma("unroll")                                                     \
    for (int t_ = 0; t_ < (H); ++t_) {                                    \
      const int a_ = k_ + t_, b_ = a_ + (H);                              \
      const int m_ = t_ << (SH);                                          \
      float vr_, vi_;                                                     \
      if (m_ == 0)      { vr_ = zr[b_]; vi_ = zi[b_]; }                   \
      else if (m_ == 8) { vr_ = zi[b_]; vi_ = -zr[b_]; }                  \
      else {                                                              \
        vr_ = zr[b_] * TW32R[m_] - zi[b_] * TW32I[m_];                    \
        vi_ = zr[b_] * TW32I[m_] + zi[b_] * TW32R[m_];                    \
      }                                                                   \
      zr[b_] = zr[a_] - vr_; zi[b_] = zi[a_] - vi_;                       \
      zr[a_] += vr_;         zi[a_] += vi_;                               \
    }                                                                     \
  }

// ---------------------------------------------------------------------------
// Kernel 1: packed complex FFT + cross-spectrum partials, HALF-LDS variant.
// Block = one (b,h,e-octet): 8 seqs z = q + i*k, but the LDS buffer holds
// only 4 planes (33.8 KB) -> 4 blocks/CU (2x occupancy). Every exchange
// runs as two half-passes; per-thread state (32 complex) stays in regs.
// Math/layouts identical to the 5-round-proven r10 kernel.
// ---------------------------------------------------------------------------
__global__ __launch_bounds__(256, 4) void fft_spec_kernel(
    const float* __restrict__ q, const float* __restrict__ k,
    float* __restrict__ partial)
{
  __shared__ float smem[8 * SSTR];   // 4 re + 4 im planes = 33824 B

  const int tid = threadIdx.x;
  const int bid = blockIdx.x;

  // work decode (r10 proven): adjacent ids = octet pair of one 64-B granule
  const int wq  = bid >> 3;
  const int xcd = bid & 7;
  const int octet = (wq & 1) | (((wq >> 1) & 3) << 1);
  const int h = (wq >> 3) & 7;
  const int b = (xcd << 2) | (wq >> 6);

  const int s = tid >> 5;     // sequence group (0..7)
  const int i = tid & 31;     // lane within group
  const int p = s & 3;        // plane for this group
  const int hg = s >> 2;      // which half this group belongs to
  constexpr int BR[32] = {0,16,8,24,4,20,12,28,2,18,10,26,6,22,14,30,
                          1,17,9,25,5,21,13,29,3,19,11,27,7,23,15,31};
  const float astep = (float)i * 6.13592315e-03f;   // 2*pi*i/1024
  float zr[32], zi[32];

  // ---- stage + row-read, two halves through the 4-plane buffer ----
  #pragma unroll
  for (int hf = 0; hf < 2; ++hf) {
    const int eq = octet * 8 + hf * 4;
    const float* qb = q + (size_t)b * 524288 + h * 64 + eq;
    const float* kb = k + (size_t)b * 524288 + h * 64 + eq;
    #pragma unroll
    for (int it = 0; it < 4; ++it) {
      const int l = it * 256 + tid;
      const float4 qv = *(const float4*)(qb + (size_t)l * 512);
      const float4 kv = *(const float4*)(kb + (size_t)l * 512);
      const int col = (l & 31) * 33 + (l >> 5);
      smem[0 * SSTR + col] = qv.x;
      smem[1 * SSTR + col] = qv.y;
      smem[2 * SSTR + col] = qv.z;
      smem[3 * SSTR + col] = qv.w;
      smem[IMOFF + 0 * SSTR + col] = kv.x;
      smem[IMOFF + 1 * SSTR + col] = kv.y;
      smem[IMOFF + 2 * SSTR + col] = kv.z;
      smem[IMOFF + 3 * SSTR + col] = kv.w;
    }
    __syncthreads();               // staged
    if (hg == hf) {
      const int base = p * SSTR + i * 33;
      #pragma unroll
      for (int c = 0; c < 32; ++c) {
        zr[BR[c]] = smem[base + c];
        zi[BR[c]] = smem[IMOFF + base + c];
      }
    }
    __syncthreads();               // reads done before next overwrite
  }

  // ---- phase 1: FFT32 + column twiddle (all threads, registers only) ----
  FFTSTAGE(2, 1, 4) FFTSTAGE(4, 2, 3) FFTSTAGE(8, 4, 2)
  FFTSTAGE(16, 8, 1) FFTSTAGE(32, 16, 0)
  #pragma unroll
  for (int k2 = 1; k2 < 32; ++k2) {      // k2==0: twiddle = 1
    float sa, ca;
    __sincosf(astep * (float)k2, &sa, &ca);
    const float nr = zr[k2] * ca + zi[k2] * sa;
    const float ni = zi[k2] * ca - zr[k2] * sa;
    zr[k2] = nr; zi[k2] = ni;
  }

  // ---- transpose exchange, two halves ----
  const int j = i;
  #pragma unroll
  for (int hx = 0; hx < 2; ++hx) {
    if (hg == hx) {
      const int base = p * SSTR + i * 33;
      #pragma unroll
      for (int k2 = 0; k2 < 32; ++k2) {
        smem[base + k2]         = zr[k2];
        smem[IMOFF + base + k2] = zi[k2];
      }
    }
    __syncthreads();
    if (hg == hx) {
      #pragma unroll
      for (int c = 0; c < 32; ++c) {
        zr[c] = smem[p * SSTR + BR[c] * 33 + j];
        zi[c] = smem[IMOFF + p * SSTR + BR[c] * 33 + j];
      }
    }
    __syncthreads();
  }

  // ---- phase 2: FFT32 (all threads) ----
  FFTSTAGE(2, 1, 4) FFTSTAGE(4, 2, 3) FFTSTAGE(8, 4, 2)
  FFTSTAGE(16, 8, 1) FFTSTAGE(32, 16, 0)
  // lane j holds Z[32*k1 + j] in (zr[k1], zi[k1])

  // ---- pairing (shfl, r10 formula) + S write/accumulate in halves ----
  const int t64 = tid & 63;
  const int pl = (t64 & 32) | ((32 - j) & 31);
  const int rowS = p * SSTR + j * 33;

  #define PAIRBATCH(K0, STORE) do {                                       \
    float sr_[16], si_[16];                                               \
    _Pragma("unroll")                                                     \
    for (int k1 = (K0); k1 < (K0) + 16; ++k1) {                           \
      float xr = __shfl(zr[31 - k1], pl, 64);                             \
      float xi = __shfl(zi[31 - k1], pl, 64);                             \
      if (j == 0) { xr = zr[(32 - k1) & 31]; xi = zi[(32 - k1) & 31]; }   \
      const float ar = zr[k1], ai = zi[k1];                               \
      sr_[k1 - (K0)] = 0.5f  * (ar * xi + ai * xr);                       \
      si_[k1 - (K0)] = 0.25f * (ar * ar + ai * ai - xr * xr - xi * xi);   \
    }                                                                     \
    _Pragma("unroll")                                                     \
    for (int m = 0; m < 16; ++m) {                                        \
      if (STORE) {                                                        \
        smem[rowS + (K0) + m]         = sr_[m];                           \
        smem[IMOFF + rowS + (K0) + m] = si_[m];                           \
      } else {                                                            \
        smem[rowS + (K0) + m]         += sr_[m];                          \
        smem[IMOFF + rowS + (K0) + m] += si_[m];                          \
      }                                                                   \
    }                                                                     \
  } while (0)

  if (hg == 0) { PAIRBATCH(0, 1); PAIRBATCH(16, 1); }
  __syncthreads();
  if (hg == 1) { PAIRBATCH(0, 0); PAIRBATCH(16, 0); }
  __syncthreads();

  // ---- reduce 4 planes -> partial[bid][v], permuted v = j*32 + k1 ----
  {
    const int jj = tid >> 3;      // 0..31
    const int kq = tid & 7;       // 0..7
    float ar4[4] = {0.f, 0.f, 0.f, 0.f};
    float ai4[4] = {0.f, 0.f, 0.f, 0.f};
    #pragma unroll
    for (int pp = 0; pp < 4; ++pp) {
      const int base = pp * SSTR + jj * 33 + kq * 4;
      #pragma unroll
      for (int m = 0; m < 4; ++m) {
        ar4[m] += smem[base + m];
        ai4[m] += smem[IMOFF + base + m];
      }
    }
    const int v = jj * 32 + kq * 4;
    *(float4*)(partial + (size_t)bid * 2048 + v) =
        make_float4(ar4[0], ar4[1], ar4[2], ar4[3]);
    *(float4*)(partial + (size_t)bid * 2048 + 1024 + v) =
        make_float4(ai4[0], ai4[1], ai4[2], ai4[3]);
  }
}

// ---------------------------------------------------------------------------
// Kernel 2: 4-way split reduce: S4[rc][v] = sum of 512 rows. grid 128.
// ---------------------------------------------------------------------------
__global__ __launch_bounds__(256) void spec_reduce(
    const float* __restrict__ partial, float* __restrict__ S4)
{
  const int t = threadIdx.x;
  const int b64 = t & 63, rq = t >> 6;
  const int vb = (blockIdx.x & 31) * 64;
  const int rc = blockIdx.x >> 5;          // 0..3
  const int v = vb + b64;
  float acc = 0.f;
  const int r0 = rc * 512 + rq * 128;
  for (int rr = r0; rr < r0 + 128; ++rr)
    acc += partial[(size_t)rr * 2048 + v];
  __shared__ float sm[4][65];
  sm[rq][b64] = acc;
  __syncthreads();
  if (t < 64)
    S4[(size_t)rc * 2048 + vb + t] =
        sm[0][t] + sm[1][t] + sm[2][t] + sm[3][t];
}

// ---------------------------------------------------------------------------
// Kernel 3: c[tau] = (1/2^24) * sum_v Re(S[v] e^{+2pi i jt(v) tau/1024}),
// jt(v) = ((v&31)<<5)|(v>>5)  (un-permute). grid 32.
// ---------------------------------------------------------------------------
__global__ __launch_bounds__(256) void corr_kernel(
    const float* __restrict__ S4, float* __restrict__ c)
{
  __shared__ float Sr[2048];
  __shared__ float sm[8][33];
  const int t = threadIdx.x;
  #pragma unroll
  for (int u = 0; u < 8; ++u) {
    const int v = u * 256 + t;
    Sr[v] = S4[v] + S4[2048 + v] + S4[4096 + v] + S4[6144 + v];
  }
  __syncthreads();

  const int tau = blockIdx.x * 32 + (t & 31);
  const int jc = t >> 5;
  float acc = 0.f;
  #pragma unroll 4
  for (int jj = 0; jj < 128; ++jj) {
    const int v = jc * 128 + jj;
    const int jt = ((v & 31) << 5) | (v >> 5);
    float s_, c_;
    __sincosf((float)((jt * tau) & 1023) * 6.13592315e-03f, &s_, &c_);
    acc += Sr[v] * c_ - Sr[1024 + v] * s_;
  }
  sm[jc][t & 31] = acc;
  __syncthreads();
  if (t < 32) {
    float r = 0.f;
    #pragma unroll
    for (int g = 0; g < 8; ++g) r += sm[g][t];
    c[blockIdx.x * 32 + t] = r * (1.0f / 16777216.0f);
  }
}

// ---------------------------------------------------------------------------
// Kernel 4: top-6 (desc, smaller-index tie-break) + softmax. 1 block.
// ---------------------------------------------------------------------------
__global__ __launch_bounds__(256) void topk_kernel(
    const float* __restrict__ c, int* __restrict__ idx_out,
    float* __restrict__ w_out)
{
  __shared__ float vals[L_SEQ];
  __shared__ float rv[256];
  __shared__ int ri[256];
  __shared__ float topv[TOPK];
  __shared__ int topi[TOPK];
  const int tid = threadIdx.x;
  for (int i = tid; i < L_SEQ; i += 256) vals[i] = c[i];
  __syncthreads();

  for (int kk = 0; kk < TOPK; ++kk) {
    float bv = -INFINITY;
    int bi = 1 << 30;
    for (int i = tid; i < L_SEQ; i += 256) {
      const float v = vals[i];
      if (v > bv || (v == bv && i < bi)) { bv = v; bi = i; }
    }
    rv[tid] = bv; ri[tid] = bi;
    __syncthreads();
    for (int off = 128; off > 0; off >>= 1) {
      if (tid < off) {
        const float v2 = rv[tid + off];
        const int i2 = ri[tid + off];
        if (v2 > rv[tid] || (v2 == rv[tid] && i2 < ri[tid])) {
          rv[tid] = v2; ri[tid] = i2;
        }
      }
      __syncthreads();
    }
    if (tid == 0) {
      topv[kk] = rv[0];
      topi[kk] = ri[0];
      vals[ri[0]] = -INFINITY;
    }
    __syncthreads();
  }

  if (tid == 0) {
    const float m = topv[0];
    float e[TOPK], sum = 0.f;
    for (int i = 0; i < TOPK; ++i) { e[i] = expf(topv[i] - m); sum += e[i]; }
    const float inv = 1.0f / sum;
    for (int i = 0; i < TOPK; ++i) { w_out[i] = e[i] * inv; idx_out[i] = topi[i]; }
  }
}

// ---------------------------------------------------------------------------
// Kernel 5: out[b,l,h,e] = sum_k w[k] * v[b,(l+idx[k])%L,h,e]
// ---------------------------------------------------------------------------
__global__ __launch_bounds__(256) void agg_kernel(
    const float* __restrict__ v, const int* __restrict__ idx,
    const float* __restrict__ w, float4* __restrict__ out)
{
  __shared__ int sidx[TOPK];
  __shared__ float sw[TOPK];
  if (threadIdx.x < TOPK) {
    sidx[threadIdx.x] = idx[threadIdx.x];
    sw[threadIdx.x] = w[threadIdx.x];
  }
  __syncthreads();

  const int i = blockIdx.x * 256 + threadIdx.x;   // 0 .. 2^22-1
  const int he4 = i & 127;
  const int l = (i >> 7) & (L_SEQ - 1);
  const int b = i >> 17;
  const float4* vb = (const float4*)v + (size_t)b * (L_SEQ * 128);

  float4 acc = make_float4(0.f, 0.f, 0.f, 0.f);
  #pragma unroll
  for (int kk = 0; kk < TOPK; ++kk) {
    const int src = (l + sidx[kk]) & (L_SEQ - 1);
    const float4 vv = vb[(size_t)src * 128 + he4];
    const float wk = sw[kk];
    acc.x += wk * vv.x; acc.y += wk * vv.y;
    acc.z += wk * vv.z; acc.w += wk * vv.w;
  }
  out[i] = acc;
}

// ---------------------------------------------------------------------------
extern "C" void kernel_launch(void* const* d_in, const int* in_sizes, int n_in,
                              void* d_out, int out_size, void* d_ws, size_t ws_size,
                              hipStream_t stream) {
  const float* q = (const float*)d_in[0];
  const float* k = (const float*)d_in[1];
  const float* v = (const float*)d_in[2];
  // d_in[3] = attn_mask (scalar 0) -- unused

  float* out = (float*)d_out;
  // scratch inside d_out (consumed before agg overwrites):
  //   partial: 2048 x 2048 floats (16 MB) at out[0]
  //   S4     : 4 x 2048 floats at out + 8M floats
  float* partial = out;
  float* S4 = out + (size_t)8388608;

  float* c    = (float*)d_ws;                          // 1024 floats
  int*   idxp = (int*)((char*)d_ws + 4096);            // 6 ints
  float* wp   = (float*)((char*)d_ws + 4096 + 64);     // 6 floats

  fft_spec_kernel<<<NFBLK, 256, 0, stream>>>(q, k, partial);
  spec_reduce<<<128, 256, 0, stream>>>(partial, S4);
  corr_kernel<<<32, 256, 0, stream>>>(S4, c);
  topk_kernel<<<1, 256, 0, stream>>>(c, idxp, wp);
  agg_kernel<<<(L_SEQ * 32 * 128) / 256, 256, 0, stream>>>(v, idxp, wp,
                                                           (float4*)out);
}

// Round 14
// 131.409 us; speedup vs baseline: 1.6318x; 1.6318x over previous
//
#include <hip/hip_runtime.h>
#include <math.h>

#define L_SEQ 1024
#define TOPK 6
#define SSTR 1057   // plane stride (floats): 32*33+1 (bank-skewed)
#define NFBLK 2048  // one (b,h,e-octet) per block

// W32^m = e^{-2*pi*i*m/32}, compile-time constants
__device__ constexpr float TW32R[16] = {
  1.f, 0.98078528f, 0.92387953f, 0.83146961f, 0.70710678f, 0.55557023f,
  0.38268343f, 0.19509032f, 0.f, -0.19509032f, -0.38268343f, -0.55557023f,
  -0.70710678f, -0.83146961f, -0.92387953f, -0.98078528f};
__device__ constexpr float TW32I[16] = {
  0.f, -0.19509032f, -0.38268343f, -0.55557023f, -0.70710678f, -0.83146961f,
  -0.92387953f, -0.98078528f, -1.f, -0.98078528f, -0.92387953f, -0.83146961f,
  -0.70710678f, -0.55557023f, -0.38268343f, -0.19509032f};

// radix-2 DIT stage; m_==0 / m_==8 (W=1 / W=-i) fold at compile time.
#define FFTSTAGE(M, H, SH)                                                \
  _Pragma("unroll")                                                       \
  for (int k_ = 0; k_ < 32; k_ += (M)) {                                  \
    _Pragma("unroll")                                                     \
    for (int t_ = 0; t_ < (H); ++t_) {                                    \
      const int a_ = k_ + t_, b_ = a_ + (H);                              \
      const int m_ = t_ << (SH);                                          \
      float vr_, vi_;                                                     \
      if (m_ == 0)      { vr_ = zr[b_]; vi_ = zi[b_]; }                   \
      else if (m_ == 8) { vr_ = zi[b_]; vi_ = -zr[b_]; }                  \
      else {                                                              \
        vr_ = zr[b_] * TW32R[m_] - zi[b_] * TW32I[m_];                    \
        vi_ = zr[b_] * TW32I[m_] + zi[b_] * TW32R[m_];                    \
      }                                                                   \
      zr[b_] = zr[a_] - vr_; zi[b_] = zi[a_] - vi_;                       \
      zr[a_] += vr_;         zi[a_] += vi_;                               \
    }                                                                     \
  }

// ---------------------------------------------------------------------------
// Kernel 1: packed complex FFT + cross-spectrum partials, TIME-SHARED-LDS.
// Block = one (b,h,e-octet): 8 seqs z = q + i*k. ONE 33.8 KB buffer (8
// planes) is time-shared between the re and im halves of every exchange;
// all 256 threads are active in every pass; per-thread state (32 complex)
// stays in registers. 4 blocks/CU (2x the r10 occupancy).
// Math/layouts identical to the 5-round-proven r10 kernel.
// ---------------------------------------------------------------------------
__global__ __launch_bounds__(256, 2) void fft_spec_kernel(
    const float* __restrict__ q, const float* __restrict__ k,
    float* __restrict__ partial)
{
  __shared__ float smem[8 * SSTR];   // 33824 B

  const int tid = threadIdx.x;
  const int bid = blockIdx.x;

  // work decode (r10 proven): adjacent ids = octet pair of one 64-B granule
  const int wq  = bid >> 3;
  const int xcd = bid & 7;
  const int octet = (wq & 1) | (((wq >> 1) & 3) << 1);
  const int h = (wq >> 3) & 7;
  const int b = (xcd << 2) | (wq >> 6);

  const float* qb = q + (size_t)b * 524288 + h * 64 + octet * 8;
  const float* kb = k + (size_t)b * 524288 + h * 64 + octet * 8;

  // issue ALL global loads up front; k held in regs until its stage pass
  const int ep = (tid & 1) * 4;
  const int lb = tid >> 1;                 // 0..127
  float4 qv[8], kv[8];
  int colv[8];
  #pragma unroll
  for (int it = 0; it < 8; ++it) {
    const int l = it * 128 + lb;
    qv[it] = *(const float4*)(qb + (size_t)l * 512 + ep);
    kv[it] = *(const float4*)(kb + (size_t)l * 512 + ep);
    colv[it] = (l & 31) * 33 + (l >> 5);
  }

  // ---- stage q (re pass) ----
  #pragma unroll
  for (int it = 0; it < 8; ++it) {
    const int col = colv[it];
    smem[(ep + 0) * SSTR + col] = qv[it].x;
    smem[(ep + 1) * SSTR + col] = qv[it].y;
    smem[(ep + 2) * SSTR + col] = qv[it].z;
    smem[(ep + 3) * SSTR + col] = qv[it].w;
  }
  __syncthreads();                                       // (1)

  const int s = tid >> 5;     // sequence (0..7)
  const int i = tid & 31;     // lane within sequence
  constexpr int BR[32] = {0,16,8,24,4,20,12,28,2,18,10,26,6,22,14,30,
                          1,17,9,25,5,21,13,29,3,19,11,27,7,23,15,31};
  const float astep = (float)i * 6.13592315e-03f;   // 2*pi*i/1024
  const int rowbase = s * SSTR + i * 33;
  float zr[32], zi[32];

  #pragma unroll
  for (int c = 0; c < 32; ++c) zr[BR[c]] = smem[rowbase + c];
  __syncthreads();                                       // (2)

  // ---- stage k (im pass) ----
  #pragma unroll
  for (int it = 0; it < 8; ++it) {
    const int col = colv[it];
    smem[(ep + 0) * SSTR + col] = kv[it].x;
    smem[(ep + 1) * SSTR + col] = kv[it].y;
    smem[(ep + 2) * SSTR + col] = kv[it].z;
    smem[(ep + 3) * SSTR + col] = kv[it].w;
  }
  __syncthreads();                                       // (3)
  #pragma unroll
  for (int c = 0; c < 32; ++c) zi[BR[c]] = smem[rowbase + c];
  __syncthreads();                                       // (4)

  // ---- phase 1: FFT32 + column twiddle (registers only) ----
  FFTSTAGE(2, 1, 4) FFTSTAGE(4, 2, 3) FFTSTAGE(8, 4, 2)
  FFTSTAGE(16, 8, 1) FFTSTAGE(32, 16, 0)
  #pragma unroll
  for (int k2 = 1; k2 < 32; ++k2) {      // k2==0: twiddle = 1
    float sa, ca;
    __sincosf(astep * (float)k2, &sa, &ca);
    const float nr = zr[k2] * ca + zi[k2] * sa;
    const float ni = zi[k2] * ca - zr[k2] * sa;
    zr[k2] = nr; zi[k2] = ni;
  }

  // ---- transpose exchange: re pass, then im pass ----
  const int j = i;
  #pragma unroll
  for (int k2 = 0; k2 < 32; ++k2) smem[rowbase + k2] = zr[k2];
  __syncthreads();                                       // (5)
  #pragma unroll
  for (int c = 0; c < 32; ++c) zr[c] = smem[s * SSTR + BR[c] * 33 + j];
  __syncthreads();                                       // (6)
  #pragma unroll
  for (int k2 = 0; k2 < 32; ++k2) smem[rowbase + k2] = zi[k2];
  __syncthreads();                                       // (7)
  #pragma unroll
  for (int c = 0; c < 32; ++c) zi[c] = smem[s * SSTR + BR[c] * 33 + j];
  __syncthreads();                                       // (8) col reads done

  // ---- phase 2: FFT32 ----
  FFTSTAGE(2, 1, 4) FFTSTAGE(4, 2, 3) FFTSTAGE(8, 4, 2)
  FFTSTAGE(16, 8, 1) FFTSTAGE(32, 16, 0)
  // lane j holds Z[32*k1 + j] in (zr[k1], zi[k1])

  // ---- pairing (r10 formula): S-re -> LDS rows now, S-im -> si_all regs ----
  const int t64 = tid & 63;
  const int pl = (t64 & 32) | ((32 - j) & 31);
  const int rowS = s * SSTR + j * 33;
  float si_all[32];

  #pragma unroll
  for (int k1 = 0; k1 < 16; ++k1) {      // uses partner regs 16..31
    float xr = __shfl(zr[31 - k1], pl, 64);
    float xi = __shfl(zi[31 - k1], pl, 64);
    if (j == 0) { xr = zr[(32 - k1) & 31]; xi = zi[(32 - k1) & 31]; }
    const float ar = zr[k1], ai = zi[k1];
    smem[rowS + k1] = 0.5f  * (ar * xi + ai * xr);
    si_all[k1]      = 0.25f * (ar * ar + ai * ai - xr * xr - xi * xi);
  }
  #pragma unroll
  for (int k1 = 16; k1 < 32; ++k1) {     // uses partner regs 0..15 (intact)
    float xr = __shfl(zr[31 - k1], pl, 64);
    float xi = __shfl(zi[31 - k1], pl, 64);
    if (j == 0) { xr = zr[(32 - k1) & 31]; xi = zi[(32 - k1) & 31]; }
    const float ar = zr[k1], ai = zi[k1];
    smem[rowS + k1] = 0.5f  * (ar * xi + ai * xr);
    si_all[k1]      = 0.25f * (ar * ar + ai * ai - xr * xr - xi * xi);
  }
  __syncthreads();                                       // (9)

  // ---- reduce 8 seqs: re pass ----
  const int jj = tid >> 3;      // row j    (0..31)
  const int kq = tid & 7;       // col quad (0..7)
  const int v = jj * 32 + kq * 4;        // permuted bin base (r10 convention)
  {
    float ar4[4] = {0.f, 0.f, 0.f, 0.f};
    #pragma unroll
    for (int pp = 0; pp < 8; ++pp) {
      const int base = pp * SSTR + jj * 33 + kq * 4;
      #pragma unroll
      for (int m = 0; m < 4; ++m) ar4[m] += smem[base + m];
    }
    *(float4*)(partial + (size_t)bid * 2048 + v) =
        make_float4(ar4[0], ar4[1], ar4[2], ar4[3]);
  }
  __syncthreads();                                       // (10)

  // ---- im pass ----
  #pragma unroll
  for (int k1 = 0; k1 < 32; ++k1) smem[rowS + k1] = si_all[k1];
  __syncthreads();                                       // (11)
  {
    float ai4[4] = {0.f, 0.f, 0.f, 0.f};
    #pragma unroll
    for (int pp = 0; pp < 8; ++pp) {
      const int base = pp * SSTR + jj * 33 + kq * 4;
      #pragma unroll
      for (int m = 0; m < 4; ++m) ai4[m] += smem[base + m];
    }
    *(float4*)(partial + (size_t)bid * 2048 + 1024 + v) =
        make_float4(ai4[0], ai4[1], ai4[2], ai4[3]);
  }
}

// ---------------------------------------------------------------------------
// Kernel 2: 4-way split reduce: S4[rc][v] = sum of 512 rows. grid 128.
// ---------------------------------------------------------------------------
__global__ __launch_bounds__(256) void spec_reduce(
    const float* __restrict__ partial, float* __restrict__ S4)
{
  const int t = threadIdx.x;
  const int b64 = t & 63, rq = t >> 6;
  const int vb = (blockIdx.x & 31) * 64;
  const int rc = blockIdx.x >> 5;          // 0..3
  const int v = vb + b64;
  float acc = 0.f;
  const int r0 = rc * 512 + rq * 128;
  for (int rr = r0; rr < r0 + 128; ++rr)
    acc += partial[(size_t)rr * 2048 + v];
  __shared__ float sm[4][65];
  sm[rq][b64] = acc;
  __syncthreads();
  if (t < 64)
    S4[(size_t)rc * 2048 + vb + t] =
        sm[0][t] + sm[1][t] + sm[2][t] + sm[3][t];
}

// ---------------------------------------------------------------------------
// Kernel 3: c[tau] = (1/2^24) * sum_v Re(S[v] e^{+2pi i jt(v) tau/1024}),
// jt(v) = ((v&31)<<5)|(v>>5)  (un-permute). grid 32.
// ---------------------------------------------------------------------------
__global__ __launch_bounds__(256) void corr_kernel(
    const float* __restrict__ S4, float* __restrict__ c)
{
  __shared__ float Sr[2048];
  __shared__ float sm[8][33];
  const int t = threadIdx.x;
  #pragma unroll
  for (int u = 0; u < 8; ++u) {
    const int v = u * 256 + t;
    Sr[v] = S4[v] + S4[2048 + v] + S4[4096 + v] + S4[6144 + v];
  }
  __syncthreads();

  const int tau = blockIdx.x * 32 + (t & 31);
  const int jc = t >> 5;
  float acc = 0.f;
  #pragma unroll 4
  for (int jj = 0; jj < 128; ++jj) {
    const int v = jc * 128 + jj;
    const int jt = ((v & 31) << 5) | (v >> 5);
    float s_, c_;
    __sincosf((float)((jt * tau) & 1023) * 6.13592315e-03f, &s_, &c_);
    acc += Sr[v] * c_ - Sr[1024 + v] * s_;
  }
  sm[jc][t & 31] = acc;
  __syncthreads();
  if (t < 32) {
    float r = 0.f;
    #pragma unroll
    for (int g = 0; g < 8; ++g) r += sm[g][t];
    c[blockIdx.x * 32 + t] = r * (1.0f / 16777216.0f);
  }
}

// ---------------------------------------------------------------------------
// Kernel 4: top-6 (desc, smaller-index tie-break) + softmax. 1 block.
// ---------------------------------------------------------------------------
__global__ __launch_bounds__(256) void topk_kernel(
    const float* __restrict__ c, int* __restrict__ idx_out,
    float* __restrict__ w_out)
{
  __shared__ float vals[L_SEQ];
  __shared__ float rv[256];
  __shared__ int ri[256];
  __shared__ float topv[TOPK];
  __shared__ int topi[TOPK];
  const int tid = threadIdx.x;
  for (int i = tid; i < L_SEQ; i += 256) vals[i] = c[i];
  __syncthreads();

  for (int kk = 0; kk < TOPK; ++kk) {
    float bv = -INFINITY;
    int bi = 1 << 30;
    for (int i = tid; i < L_SEQ; i += 256) {
      const float v = vals[i];
      if (v > bv || (v == bv && i < bi)) { bv = v; bi = i; }
    }
    rv[tid] = bv; ri[tid] = bi;
    __syncthreads();
    for (int off = 128; off > 0; off >>= 1) {
      if (tid < off) {
        const float v2 = rv[tid + off];
        const int i2 = ri[tid + off];
        if (v2 > rv[tid] || (v2 == rv[tid] && i2 < ri[tid])) {
          rv[tid] = v2; ri[tid] = i2;
        }
      }
      __syncthreads();
    }
    if (tid == 0) {
      topv[kk] = rv[0];
      topi[kk] = ri[0];
      vals[ri[0]] = -INFINITY;
    }
    __syncthreads();
  }

  if (tid == 0) {
    const float m = topv[0];
    float e[TOPK], sum = 0.f;
    for (int i = 0; i < TOPK; ++i) { e[i] = expf(topv[i] - m); sum += e[i]; }
    const float inv = 1.0f / sum;
    for (int i = 0; i < TOPK; ++i) { w_out[i] = e[i] * inv; idx_out[i] = topi[i]; }
  }
}

// ---------------------------------------------------------------------------
// Kernel 5: out[b,l,h,e] = sum_k w[k] * v[b,(l+idx[k])%L,h,e]
// ---------------------------------------------------------------------------
__global__ __launch_bounds__(256) void agg_kernel(
    const float* __restrict__ v, const int* __restrict__ idx,
    const float* __restrict__ w, float4* __restrict__ out)
{
  __shared__ int sidx[TOPK];
  __shared__ float sw[TOPK];
  if (threadIdx.x < TOPK) {
    sidx[threadIdx.x] = idx[threadIdx.x];
    sw[threadIdx.x] = w[threadIdx.x];
  }
  __syncthreads();

  const int i = blockIdx.x * 256 + threadIdx.x;   // 0 .. 2^22-1
  const int he4 = i & 127;
  const int l = (i >> 7) & (L_SEQ - 1);
  const int b = i >> 17;
  const float4* vb = (const float4*)v + (size_t)b * (L_SEQ * 128);

  float4 acc = make_float4(0.f, 0.f, 0.f, 0.f);
  #pragma unroll
  for (int kk = 0; kk < TOPK; ++kk) {
    const int src = (l + sidx[kk]) & (L_SEQ - 1);
    const float4 vv = vb[(size_t)src * 128 + he4];
    const float wk = sw[kk];
    acc.x += wk * vv.x; acc.y += wk * vv.y;
    acc.z += wk * vv.z; acc.w += wk * vv.w;
  }
  out[i] = acc;
}

// ---------------------------------------------------------------------------
extern "C" void kernel_launch(void* const* d_in, const int* in_sizes, int n_in,
                              void* d_out, int out_size, void* d_ws, size_t ws_size,
                              hipStream_t stream) {
  const float* q = (const float*)d_in[0];
  const float* k = (const float*)d_in[1];
  const float* v = (const float*)d_in[2];
  // d_in[3] = attn_mask (scalar 0) -- unused

  float* out = (float*)d_out;
  // scratch inside d_out (consumed before agg overwrites):
  //   partial: 2048 x 2048 floats (16 MB) at out[0]
  //   S4     : 4 x 2048 floats at out + 8M floats
  float* partial = out;
  float* S4 = out + (size_t)8388608;

  float* c    = (float*)d_ws;                          // 1024 floats
  int*   idxp = (int*)((char*)d_ws + 4096);            // 6 ints
  float* wp   = (float*)((char*)d_ws + 4096 + 64);     // 6 floats

  fft_spec_kernel<<<NFBLK, 256, 0, stream>>>(q, k, partial);
  spec_reduce<<<128, 256, 0, stream>>>(partial, S4);
  corr_kernel<<<32, 256, 0, stream>>>(S4, c);
  topk_kernel<<<1, 256, 0, stream>>>(c, idxp, wp);
  agg_kernel<<<(L_SEQ * 32 * 128) / 256, 256, 0, stream>>>(v, idxp, wp,
                                                           (float4*)out);
}

// Round 15
// 127.202 us; speedup vs baseline: 1.6857x; 1.0331x over previous
//
#include <hip/hip_runtime.h>
#include <math.h>

#define L_SEQ 1024
#define TOPK 6
#define SSTR 1057   // plane stride (floats): 32*33+1 (bank-skewed)
#define NFBLK 1024  // one (b,h,octet-pair) per block; 2 octets serially

// W32^m = e^{-2*pi*i*m/32}, compile-time constants
__device__ constexpr float TW32R[16] = {
  1.f, 0.98078528f, 0.92387953f, 0.83146961f, 0.70710678f, 0.55557023f,
  0.38268343f, 0.19509032f, 0.f, -0.19509032f, -0.38268343f, -0.55557023f,
  -0.70710678f, -0.83146961f, -0.92387953f, -0.98078528f};
__device__ constexpr float TW32I[16] = {
  0.f, -0.19509032f, -0.38268343f, -0.55557023f, -0.70710678f, -0.83146961f,
  -0.92387953f, -0.98078528f, -1.f, -0.98078528f, -0.92387953f, -0.83146961f,
  -0.70710678f, -0.55557023f, -0.38268343f, -0.19509032f};

// radix-2 DIT stage; m_==0 / m_==8 (W=1 / W=-i) fold at compile time.
#define FFTSTAGE(M, H, SH)                                                \
  _Pragma("unroll")                                                       \
  for (int k_ = 0; k_ < 32; k_ += (M)) {                                  \
    _Pragma("unroll")                                                     \
    for (int t_ = 0; t_ < (H); ++t_) {                                    \
      const int a_ = k_ + t_, b_ = a_ + (H);                              \
      const int m_ = t_ << (SH);                                          \
      float vr_, vi_;                                                     \
      if (m_ == 0)      { vr_ = zr[b_]; vi_ = zi[b_]; }                   \
      else if (m_ == 8) { vr_ = zi[b_]; vi_ = -zr[b_]; }                  \
      else {                                                              \
        vr_ = zr[b_] * TW32R[m_] - zi[b_] * TW32I[m_];                    \
        vi_ = zr[b_] * TW32I[m_] + zi[b_] * TW32R[m_];                    \
      }                                                                   \
      zr[b_] = zr[a_] - vr_; zi[b_] = zi[a_] - vi_;                       \
      zr[a_] += vr_;         zi[a_] += vi_;                               \
    }                                                                     \
  }

// ---------------------------------------------------------------------------
// Kernel 1: packed complex FFT + cross-spectrum partials, TIME-SHARED-LDS,
// TWO octets per block (both octets of one 64-B HBM granule -> L2 pairing
// kept inside the block). Per octet the body is the 6-round-proven r10/r14
// pipeline; the per-bin partial accumulates in registers across octets.
// ---------------------------------------------------------------------------
__global__ __launch_bounds__(256, 2) void fft_spec_kernel(
    const float* __restrict__ q, const float* __restrict__ k,
    float* __restrict__ partial)
{
  __shared__ float smem[8 * SSTR];   // 33824 B

  const int tid = threadIdx.x;
  const int bid = blockIdx.x;

  // work decode: bid&7 spreads XCDs; per XCD 128 works; one work = one
  // (b, h, octet-pair) -> both octets of a 64-B granule.
  const int wq  = bid >> 3;               // 0..127
  const int xcd = bid & 7;
  const int op  = wq & 3;                 // octet pair (octets 2op, 2op+1)
  const int h   = (wq >> 2) & 7;
  const int b   = (xcd << 2) | (wq >> 5);

  const int s = tid >> 5;     // sequence (0..7)
  const int i = tid & 31;     // lane within sequence
  constexpr int BR[32] = {0,16,8,24,4,20,12,28,2,18,10,26,6,22,14,30,
                          1,17,9,25,5,21,13,29,3,19,11,27,7,23,15,31};
  const float astep = (float)i * 6.13592315e-03f;   // 2*pi*i/1024
  const int rowbase = s * SSTR + i * 33;
  const int ep = (tid & 1) * 4;
  const int lb = tid >> 1;                // 0..127

  const int jj = tid >> 3;      // reduce: row j    (0..31)
  const int kq = tid & 7;       // reduce: col quad (0..7)
  float ar4[4] = {0.f, 0.f, 0.f, 0.f};
  float ai4[4] = {0.f, 0.f, 0.f, 0.f};

  for (int oc = 0; oc < 2; ++oc) {
    const int octet = op * 2 + oc;
    const float* qb = q + (size_t)b * 524288 + h * 64 + octet * 8;
    const float* kb = k + (size_t)b * 524288 + h * 64 + octet * 8;

    if (oc) __syncthreads();   // previous octet's reduce reads done

    // issue global loads; k held in regs until its stage pass
    float4 qv[8], kv[8];
    int colv[8];
    #pragma unroll
    for (int it = 0; it < 8; ++it) {
      const int l = it * 128 + lb;
      qv[it] = *(const float4*)(qb + (size_t)l * 512 + ep);
      kv[it] = *(const float4*)(kb + (size_t)l * 512 + ep);
      colv[it] = (l & 31) * 33 + (l >> 5);
    }

    // ---- stage q (re pass) ----
    #pragma unroll
    for (int it = 0; it < 8; ++it) {
      const int col = colv[it];
      smem[(ep + 0) * SSTR + col] = qv[it].x;
      smem[(ep + 1) * SSTR + col] = qv[it].y;
      smem[(ep + 2) * SSTR + col] = qv[it].z;
      smem[(ep + 3) * SSTR + col] = qv[it].w;
    }
    __syncthreads();                                       // (1)

    float zr[32], zi[32];
    #pragma unroll
    for (int c = 0; c < 32; ++c) zr[BR[c]] = smem[rowbase + c];
    __syncthreads();                                       // (2)

    // ---- stage k (im pass) ----
    #pragma unroll
    for (int it = 0; it < 8; ++it) {
      const int col = colv[it];
      smem[(ep + 0) * SSTR + col] = kv[it].x;
      smem[(ep + 1) * SSTR + col] = kv[it].y;
      smem[(ep + 2) * SSTR + col] = kv[it].z;
      smem[(ep + 3) * SSTR + col] = kv[it].w;
    }
    __syncthreads();                                       // (3)
    #pragma unroll
    for (int c = 0; c < 32; ++c) zi[BR[c]] = smem[rowbase + c];
    __syncthreads();                                       // (4)

    // ---- phase 1: FFT32 + column twiddle (registers only) ----
    FFTSTAGE(2, 1, 4) FFTSTAGE(4, 2, 3) FFTSTAGE(8, 4, 2)
    FFTSTAGE(16, 8, 1) FFTSTAGE(32, 16, 0)
    #pragma unroll
    for (int k2 = 1; k2 < 32; ++k2) {      // k2==0: twiddle = 1
      float sa, ca;
      __sincosf(astep * (float)k2, &sa, &ca);
      const float nr = zr[k2] * ca + zi[k2] * sa;
      const float ni = zi[k2] * ca - zr[k2] * sa;
      zr[k2] = nr; zi[k2] = ni;
    }

    // ---- transpose exchange: re pass, then im pass ----
    const int j = i;
    #pragma unroll
    for (int k2 = 0; k2 < 32; ++k2) smem[rowbase + k2] = zr[k2];
    __syncthreads();                                       // (5)
    #pragma unroll
    for (int c = 0; c < 32; ++c) zr[c] = smem[s * SSTR + BR[c] * 33 + j];
    __syncthreads();                                       // (6)
    #pragma unroll
    for (int k2 = 0; k2 < 32; ++k2) smem[rowbase + k2] = zi[k2];
    __syncthreads();                                       // (7)
    #pragma unroll
    for (int c = 0; c < 32; ++c) zi[c] = smem[s * SSTR + BR[c] * 33 + j];
    __syncthreads();                                       // (8)

    // ---- phase 2: FFT32 ----
    FFTSTAGE(2, 1, 4) FFTSTAGE(4, 2, 3) FFTSTAGE(8, 4, 2)
    FFTSTAGE(16, 8, 1) FFTSTAGE(32, 16, 0)
    // lane j holds Z[32*k1 + j] in (zr[k1], zi[k1])

    // ---- pairing: S-re -> LDS rows, S-im -> si_all regs ----
    const int t64 = tid & 63;
    const int pl = (t64 & 32) | ((32 - j) & 31);
    const int rowS = s * SSTR + j * 33;
    float si_all[32];

    #pragma unroll
    for (int k1 = 0; k1 < 16; ++k1) {      // uses partner regs 16..31
      float xr = __shfl(zr[31 - k1], pl, 64);
      float xi = __shfl(zi[31 - k1], pl, 64);
      if (j == 0) { xr = zr[(32 - k1) & 31]; xi = zi[(32 - k1) & 31]; }
      const float ar = zr[k1], ai = zi[k1];
      smem[rowS + k1] = 0.5f  * (ar * xi + ai * xr);
      si_all[k1]      = 0.25f * (ar * ar + ai * ai - xr * xr - xi * xi);
    }
    #pragma unroll
    for (int k1 = 16; k1 < 32; ++k1) {     // uses partner regs 0..15 (intact)
      float xr = __shfl(zr[31 - k1], pl, 64);
      float xi = __shfl(zi[31 - k1], pl, 64);
      if (j == 0) { xr = zr[(32 - k1) & 31]; xi = zi[(32 - k1) & 31]; }
      const float ar = zr[k1], ai = zi[k1];
      smem[rowS + k1] = 0.5f  * (ar * xi + ai * xr);
      si_all[k1]      = 0.25f * (ar * ar + ai * ai - xr * xr - xi * xi);
    }
    __syncthreads();                                       // (9)

    // ---- reduce 8 seqs: re pass (accumulate across octets) ----
    #pragma unroll
    for (int pp = 0; pp < 8; ++pp) {
      const int base = pp * SSTR + jj * 33 + kq * 4;
      #pragma unroll
      for (int m = 0; m < 4; ++m) ar4[m] += smem[base + m];
    }
    __syncthreads();                                       // (10)

    // ---- im pass ----
    const int rowS2 = s * SSTR + j * 33;
    #pragma unroll
    for (int k1 = 0; k1 < 32; ++k1) smem[rowS2 + k1] = si_all[k1];
    __syncthreads();                                       // (11)
    #pragma unroll
    for (int pp = 0; pp < 8; ++pp) {
      const int base = pp * SSTR + jj * 33 + kq * 4;
      #pragma unroll
      for (int m = 0; m < 4; ++m) ai4[m] += smem[base + m];
    }
  }

  // permuted bin base v = j*32 + k1 (r10 convention)
  const int v = jj * 32 + kq * 4;
  *(float4*)(partial + (size_t)bid * 2048 + v) =
      make_float4(ar4[0], ar4[1], ar4[2], ar4[3]);
  *(float4*)(partial + (size_t)bid * 2048 + 1024 + v) =
      make_float4(ai4[0], ai4[1], ai4[2], ai4[3]);
}

// ---------------------------------------------------------------------------
// Kernel 2: S[v] = sum_{r<1024} partial[r][v].  grid 32 x 256, one stage.
// ---------------------------------------------------------------------------
__global__ __launch_bounds__(256) void spec_reduce(
    const float* __restrict__ partial, float* __restrict__ S)
{
  const int t = threadIdx.x;
  const int b64 = t & 63, rq = t >> 6;     // 4 row-chunks of 256
  const int v = blockIdx.x * 64 + b64;
  float acc = 0.f;
  const int r0 = rq * 256;
  for (int rr = r0; rr < r0 + 256; ++rr)
    acc += partial[(size_t)rr * 2048 + v];
  __shared__ float sm[4][65];
  sm[rq][b64] = acc;
  __syncthreads();
  if (t < 64)
    S[v] = sm[0][t] + sm[1][t] + sm[2][t] + sm[3][t];
}

// ---------------------------------------------------------------------------
// Kernel 3: c[tau] = (1/2^24) * sum_v Re(S[v] e^{+2pi i jt(v) tau/1024}),
// jt(v) = ((v&31)<<5)|(v>>5)  (un-permute). grid 32.
// ---------------------------------------------------------------------------
__global__ __launch_bounds__(256) void corr_kernel(
    const float* __restrict__ S, float* __restrict__ c)
{
  __shared__ float Sr[2048];
  __shared__ float sm[8][33];
  const int t = threadIdx.x;
  #pragma unroll
  for (int u = 0; u < 8; ++u) {
    const int v = u * 256 + t;
    Sr[v] = S[v];
  }
  __syncthreads();

  const int tau = blockIdx.x * 32 + (t & 31);
  const int jc = t >> 5;
  float acc = 0.f;
  #pragma unroll 4
  for (int jj = 0; jj < 128; ++jj) {
    const int v = jc * 128 + jj;
    const int jt = ((v & 31) << 5) | (v >> 5);
    float s_, c_;
    __sincosf((float)((jt * tau) & 1023) * 6.13592315e-03f, &s_, &c_);
    acc += Sr[v] * c_ - Sr[1024 + v] * s_;
  }
  sm[jc][t & 31] = acc;
  __syncthreads();
  if (t < 32) {
    float r = 0.f;
    #pragma unroll
    for (int g = 0; g < 8; ++g) r += sm[g][t];
    c[blockIdx.x * 32 + t] = r * (1.0f / 16777216.0f);
  }
}

// ---------------------------------------------------------------------------
// Kernel 4: top-6 (desc, smaller-index tie-break) + softmax. 1 block.
// ---------------------------------------------------------------------------
__global__ __launch_bounds__(256) void topk_kernel(
    const float* __restrict__ c, int* __restrict__ idx_out,
    float* __restrict__ w_out)
{
  __shared__ float vals[L_SEQ];
  __shared__ float rv[256];
  __shared__ int ri[256];
  __shared__ float topv[TOPK];
  __shared__ int topi[TOPK];
  const int tid = threadIdx.x;
  for (int i = tid; i < L_SEQ; i += 256) vals[i] = c[i];
  __syncthreads();

  for (int kk = 0; kk < TOPK; ++kk) {
    float bv = -INFINITY;
    int bi = 1 << 30;
    for (int i = tid; i < L_SEQ; i += 256) {
      const float v = vals[i];
      if (v > bv || (v == bv && i < bi)) { bv = v; bi = i; }
    }
    rv[tid] = bv; ri[tid] = bi;
    __syncthreads();
    for (int off = 128; off > 0; off >>= 1) {
      if (tid < off) {
        const float v2 = rv[tid + off];
        const int i2 = ri[tid + off];
        if (v2 > rv[tid] || (v2 == rv[tid] && i2 < ri[tid])) {
          rv[tid] = v2; ri[tid] = i2;
        }
      }
      __syncthreads();
    }
    if (tid == 0) {
      topv[kk] = rv[0];
      topi[kk] = ri[0];
      vals[ri[0]] = -INFINITY;
    }
    __syncthreads();
  }

  if (tid == 0) {
    const float m = topv[0];
    float e[TOPK], sum = 0.f;
    for (int i = 0; i < TOPK; ++i) { e[i] = expf(topv[i] - m); sum += e[i]; }
    const float inv = 1.0f / sum;
    for (int i = 0; i < TOPK; ++i) { w_out[i] = e[i] * inv; idx_out[i] = topi[i]; }
  }
}

// ---------------------------------------------------------------------------
// Kernel 5: out[b,l,h,e] = sum_k w[k] * v[b,(l+idx[k])%L,h,e]
// ---------------------------------------------------------------------------
__global__ __launch_bounds__(256) void agg_kernel(
    const float* __restrict__ v, const int* __restrict__ idx,
    const float* __restrict__ w, float4* __restrict__ out)
{
  __shared__ int sidx[TOPK];
  __shared__ float sw[TOPK];
  if (threadIdx.x < TOPK) {
    sidx[threadIdx.x] = idx[threadIdx.x];
    sw[threadIdx.x] = w[threadIdx.x];
  }
  __syncthreads();

  const int i = blockIdx.x * 256 + threadIdx.x;   // 0 .. 2^22-1
  const int he4 = i & 127;
  const int l = (i >> 7) & (L_SEQ - 1);
  const int b = i >> 17;
  const float4* vb = (const float4*)v + (size_t)b * (L_SEQ * 128);

  float4 acc = make_float4(0.f, 0.f, 0.f, 0.f);
  #pragma unroll
  for (int kk = 0; kk < TOPK; ++kk) {
    const int src = (l + sidx[kk]) & (L_SEQ - 1);
    const float4 vv = vb[(size_t)src * 128 + he4];
    const float wk = sw[kk];
    acc.x += wk * vv.x; acc.y += wk * vv.y;
    acc.z += wk * vv.z; acc.w += wk * vv.w;
  }
  out[i] = acc;
}

// ---------------------------------------------------------------------------
extern "C" void kernel_launch(void* const* d_in, const int* in_sizes, int n_in,
                              void* d_out, int out_size, void* d_ws, size_t ws_size,
                              hipStream_t stream) {
  const float* q = (const float*)d_in[0];
  const float* k = (const float*)d_in[1];
  const float* v = (const float*)d_in[2];
  // d_in[3] = attn_mask (scalar 0) -- unused

  float* out = (float*)d_out;
  // scratch inside d_out (consumed before agg overwrites):
  //   partial: 1024 x 2048 floats (8 MB) at out[0]
  float* partial = out;

  float* c    = (float*)d_ws;                          // 1024 floats
  int*   idxp = (int*)((char*)d_ws + 4096);            // 6 ints
  float* wp   = (float*)((char*)d_ws + 4096 + 64);     // 6 floats
  float* S    = (float*)((char*)d_ws + 8192);          // 2048 floats

  fft_spec_kernel<<<NFBLK, 256, 0, stream>>>(q, k, partial);
  spec_reduce<<<32, 256, 0, stream>>>(partial, S);
  corr_kernel<<<32, 256, 0, stream>>>(S, c);
  topk_kernel<<<1, 256, 0, stream>>>(c, idxp, wp);
  agg_kernel<<<(L_SEQ * 32 * 128) / 256, 256, 0, stream>>>(v, idxp, wp,
                                                           (float4*)out);
}